// Round 11
// baseline (130.959 us; speedup 1.0000x reference)
//
#include <hip/hip_runtime.h>

typedef __attribute__((ext_vector_type(8))) short short8;
typedef __attribute__((ext_vector_type(4))) float f32x4;

#define IN_DIM 256
#define OUT_DIM 256
#define NB 16                 // padded basis count (13 real + 3 zero)
#define KDIM (IN_DIM * NB)    // 4096
#define TM 64
#define TN 64
#define BK 128                // 8 i-values per K-step (256 B per A row)
#define STEPS 32              // KDIM / BK  (R10 bug: old macro evaluated to 4)
#define ABUF 16384            // bytes per A double-buffer half (TM*BK*2)

__device__ __forceinline__ unsigned short f2bf(float f) {
  union { float f; unsigned int u; } v; v.f = f;
  unsigned int r = v.u + 0x7fffu + ((v.u >> 16) & 1u);  // RNE
  return (unsigned short)(r >> 16);
}

// branchless cubic B-spline row: 16 bf16 slots (packed into d[8] u32), 4 nonzeros at c..c+3
__device__ __forceinline__ void spline_row(float xv, unsigned* d) {
  float xc = fminf(fmaxf(xv, -1.0f), 1.0f - 1e-6f);
  float u = (xc + 1.0f) * 5.0f;            // h = 0.2
  int c = (int)u;
  c = c > 9 ? 9 : (c < 0 ? 0 : c);
  float tt = u - (float)c;
  float omt = 1.0f - tt;
  float t2 = tt * tt, t3 = t2 * tt;
  float b0 = omt * omt * omt * (1.0f / 6.0f);
  float b1 = (3.0f * t3 - 6.0f * t2 + 4.0f) * (1.0f / 6.0f);
  float b2 = (-3.0f * t3 + 3.0f * t2 + 3.0f * tt + 1.0f) * (1.0f / 6.0f);
  float b3 = t3 * (1.0f / 6.0f);
  unsigned h0 = f2bf(b0), h1 = f2bf(b1), h2 = f2bf(b2), h3 = f2bf(b3);
  const int a = c >> 1;
  const bool odd = (c & 1) != 0;
  unsigned p01 = h0 | (h1 << 16);
  unsigned p23 = h2 | (h3 << 16);
  unsigned A0 = odd ? (h0 << 16) : p01;
  unsigned A1 = odd ? (h1 | (h2 << 16)) : p23;
  unsigned A2 = odd ? h3 : 0u;
#pragma unroll
  for (int j = 0; j < 8; ++j) {
    unsigned v = (j == a) ? A0 : 0u;
    v = (j == a + 1) ? A1 : v;
    v = (j == a + 2) ? A2 : v;
    d[j] = v;
  }
}

// --- prep: BmT[o][i*16+n] = bf16( sum_e softmax(gating[i,o,:])[e] * coeff[e,n] )
// (no output zeroing: gemm does plain stores, no atomics)
__global__ __launch_bounds__(256) void kan_prep(const float* __restrict__ coeff,
                                                const float* __restrict__ gw,
                                                unsigned short* __restrict__ BmT) {
  __shared__ float csh[104];
  __shared__ unsigned short tile[16][256];   // [o_loc][il*16+n]
  const int t = threadIdx.x;
  if (t < 104) csh[t] = coeff[t];
  __syncthreads();
  const int otile = blockIdx.x, itile = blockIdx.y;
  const int il = t >> 4, ol = t & 15;
  const int i = itile * 16 + il;
  const int o = otile * 16 + ol;
  const float* g = gw + (size_t)(i * OUT_DIM + o) * 8;
  float4 g0 = *(const float4*)g;
  float4 g1 = *(const float4*)(g + 4);
  float ge[8] = {g0.x, g0.y, g0.z, g0.w, g1.x, g1.y, g1.z, g1.w};
  float mx = ge[0];
#pragma unroll
  for (int e = 1; e < 8; ++e) mx = fmaxf(mx, ge[e]);
  float p[8]; float s = 0.f;
#pragma unroll
  for (int e = 0; e < 8; ++e) { p[e] = __expf(ge[e] - mx); s += p[e]; }
  const float inv = 1.0f / s;
  unsigned short row[16];
#pragma unroll
  for (int n = 0; n < 13; ++n) {
    float w = 0.f;
#pragma unroll
    for (int e = 0; e < 8; ++e) w += p[e] * csh[e * 13 + n];
    row[n] = f2bf(w * inv);
  }
  row[13] = 0; row[14] = 0; row[15] = 0;
  int4* dst = (int4*)&tile[ol][il * 16];
  dst[0] = *(const int4*)&row[0];
  dst[1] = *(const int4*)&row[8];
  __syncthreads();
  const int oo = t >> 4, ck = t & 15;
  int4 v0 = *(const int4*)&tile[oo][ck * 16];
  int4 v1 = *(const int4*)&tile[oo][ck * 16 + 8];
  int4* out4 = (int4*)(BmT + (size_t)(otile * 16 + oo) * KDIM + itile * 256 + ck * 16);
  out4[0] = v0;
  out4[1] = v1;
}

// --- fused basis + GEMM, hybrid structure:
//  * A (spline basis, K=4096) staged in LDS, double-buffered, XOR-swizzled;
//    pure-VALU eval (no tables), 16B write + 16B read per lane-eval.
//  * B (BmT) loaded DIRECTLY global->register per fragment (2 MB, L2-resident);
//    no LDS staging, no global_load_lds, no vmcnt anywhere.
//  * raw s_barrier + lgkmcnt(0)-only wait per step -> B/x register loads
//    pipeline freely across steps (no vmcnt(0) drain = the R0-R8 wall).
// TM=64 x TN=64, 4 waves (2M x 2N, 32x32 each), grid (128,4)=512 blocks (2/CU),
// BK=128 (4 MFMA-slices per step, 32 steps), direct coalesced stores.
__global__ __launch_bounds__(256, 2) void kan_gemm(const float* __restrict__ x,
                                                   const unsigned short* __restrict__ BmT,
                                                   float* __restrict__ out) {
  __shared__ unsigned short Ash[2][TM * BK];   // 2 x 16384 B, swizzled [row][128k]

  const int t = threadIdx.x;
  const int lane = t & 63;
  const int wave = t >> 6;                     // 4 waves: 2M x 2N
  const int wm = wave >> 1, wn = wave & 1;
  const int mb = blockIdx.x * TM;
  const int ob = blockIdx.y * TN;

  // A stager: thread -> (row r = t>>2, i-pair ip = t&3); 2 spline evals / step.
  const int r = t >> 2, ip = t & 3;
  const float* xp = x + (size_t)(mb + r) * IN_DIM + 2 * ip;   // step s at xp[8s] (float2)
  char* const ab0 = (char*)&Ash[0][0] + r * 256;
  const int msw = r & 7;
  const int aw0 = ((4 * ip + 0) ^ msw) << 4;
  const int aw1 = ((4 * ip + 1) ^ msw) << 4;
  const int aw2 = ((4 * ip + 2) ^ msw) << 4;
  const int aw3 = ((4 * ip + 3) ^ msw) << 4;

  const int rl = lane & 15, qd = lane >> 4;

  // B direct-load pointers: frag f element j = BmT[ob+wn*32+f*16+rl][k], k=s*128+ks*32+qd*8+j
  const unsigned short* bp[2];
#pragma unroll
  for (int f = 0; f < 2; ++f)
    bp[f] = BmT + (size_t)(ob + wn * 32 + f * 16 + rl) * KDIM + qd * 8;

  // A fragment read addresses (swizzled); constant across steps (buffer offset added at use)
  int aadr[4][2];
#pragma unroll
  for (int ks = 0; ks < 4; ++ks)
#pragma unroll
    for (int f = 0; f < 2; ++f) {
      const int ro = wm * 32 + f * 16 + rl;
      aadr[ks][f] = ro * 256 + (((qd | (ks << 2)) ^ (ro & 7)) << 4);
    }

  f32x4 acc[2][2];
#pragma unroll
  for (int a = 0; a < 2; ++a)
#pragma unroll
    for (int b = 0; b < 2; ++b) acc[a][b] = (f32x4){0.f, 0.f, 0.f, 0.f};

  // ---- prologue: spline-stage step 0 into buf 0
  {
    float2 xv = *(const float2*)xp;
    unsigned d[8];
    spline_row(xv.x, d);
    *(int4*)(ab0 + aw0) = *(const int4*)&d[0];
    *(int4*)(ab0 + aw1) = *(const int4*)&d[4];
    spline_row(xv.y, d);
    *(int4*)(ab0 + aw2) = *(const int4*)&d[0];
    *(int4*)(ab0 + aw3) = *(const int4*)&d[4];
    asm volatile("s_waitcnt lgkmcnt(0)" ::: "memory");
    __builtin_amdgcn_sched_barrier(0);
    __builtin_amdgcn_s_barrier();
  }

  for (int s = 0; s < STEPS; ++s) {
    const int cur = s & 1;
    // x prefetch for step s+1 (register load; compiler-tracked vmcnt)
    float2 xn = {0.f, 0.f};
    if (s + 1 < STEPS) xn = *(const float2*)(xp + 8 * (s + 1));
    // 4 MFMA-slices on A[cur] + direct-global B
    const char* Ac = (const char*)&Ash[0][0] + cur * ABUF;
#pragma unroll
    for (int ks = 0; ks < 4; ++ks) {
      short8 bfr[2], af[2];
#pragma unroll
      for (int f = 0; f < 2; ++f) bfr[f] = *(const short8*)(bp[f] + s * 128 + ks * 32);
#pragma unroll
      for (int f = 0; f < 2; ++f) af[f] = *(const short8*)(Ac + aadr[ks][f]);
#pragma unroll
      for (int mf = 0; mf < 2; ++mf)
#pragma unroll
        for (int nf = 0; nf < 2; ++nf)
          acc[mf][nf] = __builtin_amdgcn_mfma_f32_16x16x32_bf16(af[mf], bfr[nf], acc[mf][nf], 0, 0, 0);
    }
    // spline-stage step s+1 into buf[1-cur]
    if (s + 1 < STEPS) {
      unsigned d[8];
      char* an = ab0 + (1 - cur) * ABUF;
      spline_row(xn.x, d);
      *(int4*)(an + aw0) = *(const int4*)&d[0];
      *(int4*)(an + aw1) = *(const int4*)&d[4];
      spline_row(xn.y, d);
      *(int4*)(an + aw2) = *(const int4*)&d[0];
      *(int4*)(an + aw3) = *(const int4*)&d[4];
    }
    // one raw barrier per step: LDS-only drain (B/x loads stay in flight)
    asm volatile("s_waitcnt lgkmcnt(0)" ::: "memory");
    __builtin_amdgcn_sched_barrier(0);
    __builtin_amdgcn_s_barrier();
  }

  // epilogue: direct coalesced stores (each output element written exactly once)
#pragma unroll
  for (int mf = 0; mf < 2; ++mf)
#pragma unroll
    for (int nf = 0; nf < 2; ++nf)
#pragma unroll
      for (int q = 0; q < 4; ++q) {
        int row = mb + wm * 32 + mf * 16 + (qd << 2) + q;
        int col = ob + wn * 32 + nf * 16 + rl;
        out[(size_t)row * OUT_DIM + col] = acc[mf][nf][q];
      }
}

extern "C" void kernel_launch(void* const* d_in, const int* in_sizes, int n_in,
                              void* d_out, int out_size, void* d_ws, size_t ws_size,
                              hipStream_t stream) {
  const float* x     = (const float*)d_in[0];   // (4,2048,256) f32
  const float* coeff = (const float*)d_in[1];   // (8,13) f32
  const float* gw    = (const float*)d_in[2];   // (256,256,8) f32
  float* out = (float*)d_out;                   // (4,2048,256) f32
  unsigned short* BmT = (unsigned short*)d_ws;  // 256 x 4096 bf16 = 2 MB

  kan_prep<<<dim3(16, 16), dim3(256), 0, stream>>>(coeff, gw, BmT);
  dim3 grid(8192 / TM, OUT_DIM / TN);
  kan_gemm<<<grid, dim3(256), 0, stream>>>(x, BmT, out);
}